// Round 1
// baseline (3526.966 us; speedup 1.0000x reference)
//
#include <hip/hip_runtime.h>
#include <hip/hip_bf16.h>
#include <stdint.h>

typedef __bf16 bf16x8 __attribute__((ext_vector_type(8)));
typedef float f32x4 __attribute__((ext_vector_type(4)));
typedef unsigned short u16;

#define B_  64
#define S_  256
#define I_  1024
#define H_  1024
#define NG  4096      /* 4*H */
#define M_  16384     /* S*B */

using gvoid_p = const __attribute__((address_space(1))) void*;
using lvoid_p = __attribute__((address_space(3))) void*;

__device__ __forceinline__ void gl_lds16(const void* g, void* l) {
  __builtin_amdgcn_global_load_lds((gvoid_p)g, (lvoid_p)l, 16, 0, 0);
}

__device__ __forceinline__ u16 f2bf(float f) {
  __hip_bfloat16 h = __float2bfloat16(f);
  union { __hip_bfloat16 h; u16 u; } c; c.h = h; return c.u;
}
__device__ __forceinline__ float bf2f(u16 u) {
  union { u16 u; __hip_bfloat16 h; } c; c.u = u; return __bfloat162float(c.h);
}

// ---- fp32 -> bf16 converts -------------------------------------------------
// x: (B,S,I) fp32 -> xb row-major [(s*64+b)][I] bf16 (GEMM A layout)
__global__ void cvt_x(const float* __restrict__ x, u16* __restrict__ xb) {
  int bid = blockIdx.x;            // = s*64 + b
  int b = bid & 63, s = bid >> 6;
  int t = threadIdx.x;
  float4 v = ((const float4*)(x + (size_t)b * (S_ * I_) + (size_t)s * I_))[t];
  ushort4 o;
  o.x = f2bf(v.x); o.y = f2bf(v.y); o.z = f2bf(v.z); o.w = f2bf(v.w);
  ((ushort4*)(xb + (size_t)bid * I_))[t] = o;
}

// w: [4096][1024] fp32 -> bf16 same layout (4096 blocks x 256 thr x 4 elem)
__global__ void cvt_w(const float* __restrict__ w, u16* __restrict__ wb) {
  size_t i = ((size_t)blockIdx.x * 256 + threadIdx.x) * 4;
  float4 v = *(const float4*)(w + i);
  ushort4 o;
  o.x = f2bf(v.x); o.y = f2bf(v.y); o.z = f2bf(v.z); o.w = f2bf(v.w);
  *(ushort4*)(wb + i) = o;
}

// ---- big input GEMM: C[16384][4096] = A[16384][1024] * BT[4096][1024]^T ----
// m97 structure: 128x128 tile, BK=32, 4 waves 2x2, global_load_lds width 16.
__global__ __launch_bounds__(256) void gemm_bt(const u16* __restrict__ A,
                                               const u16* __restrict__ BT,
                                               u16* __restrict__ C) {
  __shared__ u16 As[128 * 32];
  __shared__ u16 Bs[128 * 32];
  const int tid  = threadIdx.x;
  const int lane = tid & 63;
  const int wv   = tid >> 6;
  const int wm   = wv & 1, wn = wv >> 1;
  const int quad = lane >> 4, l16 = lane & 15;
  const int m0 = blockIdx.y * 128;
  const int n0 = blockIdx.x * 128;

  // staging chunks: chunk c covers tile bytes [c*16, c*16+16): row=c>>2, k8=(c&3)*8
  const int c0i = tid, c1i = tid + 256;
  const int ar0 = c0i >> 2, ak0 = (c0i & 3) * 8;
  const int ar1 = c1i >> 2, ak1 = (c1i & 3) * 8;

  f32x4 acc[4][4] = {};

  for (int kt = 0; kt < 32; ++kt) {
    const int k0 = kt * 32;
    __syncthreads();   // previous tile fully consumed
    gl_lds16(A + (size_t)(m0 + ar0) * I_ + k0 + ak0, &As[c0i * 8]);
    gl_lds16(A + (size_t)(m0 + ar1) * I_ + k0 + ak1, &As[c1i * 8]);
    gl_lds16(BT + (size_t)(n0 + ar0) * I_ + k0 + ak0, &Bs[c0i * 8]);
    gl_lds16(BT + (size_t)(n0 + ar1) * I_ + k0 + ak1, &Bs[c1i * 8]);
    __syncthreads();   // compiler drains vmcnt before barrier

    bf16x8 af[4], bfr[4];
#pragma unroll
    for (int mi = 0; mi < 4; ++mi)
      af[mi] = *(const bf16x8*)&As[(wm * 64 + mi * 16 + l16) * 32 + quad * 8];
#pragma unroll
    for (int ni = 0; ni < 4; ++ni)
      bfr[ni] = *(const bf16x8*)&Bs[(wn * 64 + ni * 16 + l16) * 32 + quad * 8];
#pragma unroll
    for (int mi = 0; mi < 4; ++mi)
#pragma unroll
      for (int ni = 0; ni < 4; ++ni)
        acc[mi][ni] = __builtin_amdgcn_mfma_f32_16x16x32_bf16(af[mi], bfr[ni], acc[mi][ni], 0, 0, 0);
  }

#pragma unroll
  for (int mi = 0; mi < 4; ++mi)
#pragma unroll
    for (int ni = 0; ni < 4; ++ni) {
      const int col = n0 + wn * 64 + ni * 16 + l16;
#pragma unroll
      for (int r = 0; r < 4; ++r) {
        const int row = m0 + wm * 64 + mi * 16 + quad * 4 + r;
        C[(size_t)row * NG + col] = f2bf(acc[mi][ni][r]);
      }
    }
}

// ---- persistent recurrent kernel ------------------------------------------
__device__ __forceinline__ void grid_barrier(unsigned* bar, unsigned target) {
  __syncthreads();
  if (threadIdx.x == 0) {
    __hip_atomic_fetch_add(bar, 1u, __ATOMIC_RELEASE, __HIP_MEMORY_SCOPE_AGENT);
    while (__hip_atomic_load(bar, __ATOMIC_RELAXED, __HIP_MEMORY_SCOPE_AGENT) < target)
      __builtin_amdgcn_s_sleep(1);
    __threadfence();   // acquire: invalidate L1/L2 so remote h writes are seen
  }
  __syncthreads();
}

#define HSTR 136   /* 128 + 8 bf16 pad; 272B row stride keeps 16B align, 2-way banks */

// 64 blocks x 256 thr. Block w owns h-cols [16w,16w+16) for all 4 gates.
// wave g = gate. w_h fragments live in registers (128 VGPR/wave) for all 256 steps.
__global__ __launch_bounds__(256, 1) void lstm_rec(
    const u16* __restrict__ whb,     // [4096][1024] bf16
    const u16* __restrict__ gxb,     // [(s*64+b)][4096] bf16
    const float* __restrict__ b_i, const float* __restrict__ b_h,
    const float* __restrict__ h0, const float* __restrict__ c0,
    u16* hbuf,                       // [2][64][1024] bf16 (double buffer)
    float* __restrict__ out,         // hidden[64][256][1024], hN[64][1024], cN[64][1024]
    unsigned* bar) {
  const int tid = threadIdx.x, lane = tid & 63, g = tid >> 6;
  const int quad = lane >> 4, col = lane & 15;
  const int w = blockIdx.x, jlo = w * 16;

  __shared__ u16 hs[2][64 * HSTR];   // staged h chunk [64 rows][128 k], dbuf
  __shared__ float ex[4][64][17];    // gate exchange, padded

  // --- preload w_h B-fragments into registers (16 n-rows x 1024 K per gate) ---
  bf16x8 barr[32];
  {
    const u16* wrow = whb + (size_t)(g * H_ + jlo + col) * I_ + quad * 8;
#pragma unroll
    for (int kk = 0; kk < 32; ++kk)
      barr[kk] = *(const bf16x8*)(wrow + kk * 32);
  }
  const float biasv = b_i[g * H_ + jlo + col] + b_h[g * H_ + jlo + col];

  // --- per-thread elementwise ownership: row = batch, 4 contiguous cols ---
  const int erow = tid >> 2, ec0 = (tid & 3) * 4;
  float c_reg[4], h_reg[4];
  {
    ushort4 hbv;
#pragma unroll
    for (int j = 0; j < 4; ++j) {
      const int cc = jlo + ec0 + j;
      c_reg[j] = c0[(size_t)erow * H_ + cc];
      h_reg[j] = h0[(size_t)erow * H_ + cc];
    }
    hbv.x = f2bf(h_reg[0]); hbv.y = f2bf(h_reg[1]);
    hbv.z = f2bf(h_reg[2]); hbv.w = f2bf(h_reg[3]);
    *(ushort4*)(hbuf + (size_t)erow * H_ + jlo + ec0) = hbv;   // buffer 0
  }

#pragma unroll 1
  for (int s = 0; s < S_; ++s) {
    const u16* hb = hbuf + (size_t)(s & 1) * (B_ * H_);
    u16* hw = hbuf + (size_t)((s + 1) & 1) * (B_ * H_);

    // prefetch gx for this step (independent of h -> issue before barrier)
    const u16* gxp = gxb + (size_t)s * (B_ * NG) + g * H_ + jlo + col;
    float gxv[16];
#pragma unroll
    for (int mi = 0; mi < 4; ++mi)
#pragma unroll
      for (int r = 0; r < 4; ++r)
        gxv[mi * 4 + r] = bf2f(gxp[(size_t)(mi * 16 + quad * 4 + r) * NG]);

    grid_barrier(bar, 64u * (s + 1));   // previous step's h now visible

    // --- stage chunk 0 (coalesced: 16 lanes cover 256B of one h row) ---
    {
      bf16x8 sv[4];
#pragma unroll
      for (int r = 0; r < 4; ++r) {
        const int c = tid + 256 * r;
        sv[r] = *(const bf16x8*)(hb + (size_t)(c >> 4) * H_ + (c & 15) * 8);
      }
#pragma unroll
      for (int r = 0; r < 4; ++r) {
        const int c = tid + 256 * r;
        *(bf16x8*)&hs[0][(c >> 4) * HSTR + (c & 15) * 8] = sv[r];
      }
    }
    __syncthreads();

    f32x4 acc[4] = {};
#pragma unroll
    for (int kc = 0; kc < 8; ++kc) {
      bf16x8 nv[4];
      if (kc < 7) {   // issue next-chunk global loads early (hide under MFMA)
#pragma unroll
        for (int r = 0; r < 4; ++r) {
          const int c = tid + 256 * r;
          nv[r] = *(const bf16x8*)(hb + (size_t)(c >> 4) * H_ + (kc + 1) * 128 + (c & 15) * 8);
        }
      }
      const u16* hsc = hs[kc & 1];
#pragma unroll
      for (int kk = 0; kk < 4; ++kk)
#pragma unroll
        for (int mi = 0; mi < 4; ++mi) {
          bf16x8 afr = *(const bf16x8*)&hsc[(mi * 16 + col) * HSTR + kk * 32 + quad * 8];
          acc[mi] = __builtin_amdgcn_mfma_f32_16x16x32_bf16(afr, barr[kc * 4 + kk], acc[mi], 0, 0, 0);
        }
      if (kc < 7) {
#pragma unroll
        for (int r = 0; r < 4; ++r) {
          const int c = tid + 256 * r;
          *(bf16x8*)&hs[(kc + 1) & 1][(c >> 4) * HSTR + (c & 15) * 8] = nv[r];
        }
      }
      __syncthreads();
    }

    // --- wave-domain epilogue: bias + gx, activation, exchange via LDS ---
#pragma unroll
    for (int mi = 0; mi < 4; ++mi)
#pragma unroll
      for (int r = 0; r < 4; ++r) {
        const int b = mi * 16 + quad * 4 + r;
        const float v = acc[mi][r] + biasv + gxv[mi * 4 + r];
        ex[g][b][col] = (g == 2) ? tanhf(v) : 1.f / (1.f + __expf(-v));
      }
    __syncthreads();

    // --- thread-domain state update ---
    {
      ushort4 hbv;
#pragma unroll
      for (int j = 0; j < 4; ++j) {
        const int cc = ec0 + j;
        const float iv = ex[0][erow][cc];
        const float fv = ex[1][erow][cc];
        const float gv = ex[2][erow][cc];
        const float ov = ex[3][erow][cc];
        const float c = fv * c_reg[j] + iv * gv;
        c_reg[j] = c;
        h_reg[j] = ov * tanhf(c);
      }
      float4 hv = make_float4(h_reg[0], h_reg[1], h_reg[2], h_reg[3]);
      *(float4*)(out + (size_t)erow * (S_ * H_) + (size_t)s * H_ + jlo + ec0) = hv;
      hbv.x = f2bf(h_reg[0]); hbv.y = f2bf(h_reg[1]);
      hbv.z = f2bf(h_reg[2]); hbv.w = f2bf(h_reg[3]);
      *(ushort4*)(hw + (size_t)erow * H_ + jlo + ec0) = hbv;
    }
    // ex reuse is protected by next step's grid_barrier (contains syncthreads)
  }

  // --- final hN, cN ---
  {
    const size_t base = (size_t)B_ * S_ * H_;
    float4 hv = make_float4(h_reg[0], h_reg[1], h_reg[2], h_reg[3]);
    float4 cv = make_float4(c_reg[0], c_reg[1], c_reg[2], c_reg[3]);
    *(float4*)(out + base + (size_t)erow * H_ + jlo + ec0) = hv;
    *(float4*)(out + base + (size_t)B_ * H_ + (size_t)erow * H_ + jlo + ec0) = cv;
  }
}

// ---- launch ----------------------------------------------------------------
extern "C" void kernel_launch(void* const* d_in, const int* in_sizes, int n_in,
                              void* d_out, int out_size, void* d_ws, size_t ws_size,
                              hipStream_t stream) {
  const float* x  = (const float*)d_in[0];
  const float* h0 = (const float*)d_in[1];
  const float* c0 = (const float*)d_in[2];
  const float* wi = (const float*)d_in[3];
  const float* wh = (const float*)d_in[4];
  const float* bi = (const float*)d_in[5];
  const float* bh = (const float*)d_in[6];
  float* out = (float*)d_out;

  char* ws = (char*)d_ws;
  u16* xb   = (u16*)(ws);                   //  33,554,432 B
  u16* wib  = (u16*)(ws + 33554432);        //   8,388,608 B
  u16* whb  = (u16*)(ws + 41943040);        //   8,388,608 B
  u16* gxb  = (u16*)(ws + 50331648);        // 134,217,728 B
  u16* hbuf = (u16*)(ws + 184549376);       //     262,144 B (double buffer)
  unsigned* bar = (unsigned*)(ws + 184811520);

  cvt_x<<<M_, 256, 0, stream>>>(x, xb);
  cvt_w<<<4096, 256, 0, stream>>>(wi, wib);
  cvt_w<<<4096, 256, 0, stream>>>(wh, whb);
  gemm_bt<<<dim3(NG / 128, M_ / 128), 256, 0, stream>>>(xb, wib, gxb);
  hipMemsetAsync(bar, 0, 4, stream);

  void* args[] = { &whb, &gxb, &bi, &bh, &h0, &c0, &hbuf, &out, &bar };
  hipLaunchCooperativeKernel((void*)lstm_rec, dim3(64), dim3(256), args, 0, stream);
}